// Round 10
// baseline (99.278 us; speedup 1.0000x reference)
//
#include <hip/hip_runtime.h>

#define NC 9
#define BLOCK 256
#define TPT 4                        // tokens per thread
#define CHUNK (BLOCK * TPT)          // 1024 tokens per block-chunk
#define GRID 4096

// partials layout: partials[block*32 + idx], idx 0..8 = sum w*p_c,
// 9..17 = sum onehot*w*p_c, 18..26 = sum onehot*w

__global__ __launch_bounds__(BLOCK) void dice_partial(
    const float* __restrict__ logits,
    const int*   __restrict__ targets,
    float*       __restrict__ partials,
    int n)
{
    // per-wave private 9216-B staging regions: no cross-wave sharing -> no barriers
    __shared__ __align__(16) float4 lds[4 * 576];   // 36864 B
    __shared__ float red[4][32];

    float sWP[NC], sI[NC], sOH[NC];
    #pragma unroll
    for (int c = 0; c < NC; ++c) { sWP[c] = 0.f; sI[c] = 0.f; sOH[c] = 0.f; }

    const int tid = threadIdx.x;
    const int w   = tid >> 6;        // wave 0..3
    const int l   = tid & 63;        // lane
    const int nChunks = (n + CHUNK - 1) / CHUNK;

    for (int blk = blockIdx.x; blk < nChunks; blk += gridDim.x) {
        const int tokBase = blk * CHUNK;

        if (tokBase + CHUNK <= n) {
            // ---- stage: wave w copies its private 256-token (9216 B) segment,
            //      9 x perfectly-coalesced dwordx4 (1024 contiguous B per instr) ----
            const float4* g4 = reinterpret_cast<const float4*>(logits)
                             + (size_t)blk * (CHUNK * NC / 4) + w * 576;
            float4* Lw = lds + w * 576;
            float4 tmp[9];
            #pragma unroll
            for (int k = 0; k < 9; ++k) tmp[k] = g4[k * 64 + l];
            #pragma unroll
            for (int k = 0; k < 9; ++k) Lw[k * 64 + l] = tmp[k];

            // ---- transpose read: lane l's 4 consecutive tokens (144 B),
            //      9 x ds_read_b128 at 36-dword stride: conflict-free ----
            float f[TPT * NC];
            #pragma unroll
            for (int k = 0; k < 9; ++k) {
                const float4 q = Lw[l * 9 + k];     // same-wave LDS: lgkmcnt only
                f[4 * k]     = q.x;
                f[4 * k + 1] = q.y;
                f[4 * k + 2] = q.z;
                f[4 * k + 3] = q.w;
            }

            const int tok0 = tokBase + tid * TPT;   // == tokBase + w*256 + l*4
            const int4 t4  = *reinterpret_cast<const int4*>(targets + tok0);
            int tg[TPT];
            tg[0] = t4.x; tg[1] = t4.y; tg[2] = t4.z; tg[3] = t4.w;
            const int  tExtra = (tok0 + TPT < n) ? targets[tok0 + TPT] : 0;
            const bool lastIsGlobalEnd = (tok0 + TPT == n);

            #pragma unroll
            for (int j = 0; j < TPT; ++j) {
                const int  t    = tg[j];
                const bool last = (j == TPT - 1) && lastIsGlobalEnd;
                const int  tn   = (j < TPT - 1) ? tg[j + 1] : tExtra;

                float wt = 1.0f;
                if (t == 1) wt = 3.0f;                    // B-PERSON
                const int nxt_dup = last ? t : tn;        // shift padded with last elem
                if (t == 2 && nxt_dup != 2) wt = 2.5f;    // I-PERSON end
                if (!last && tn == 1) wt = 1.5f;          // token before a B (overwrites)

                float v[NC];
                #pragma unroll
                for (int c = 0; c < NC; ++c) v[c] = f[j * NC + c];
                float m = v[0];
                #pragma unroll
                for (int c = 1; c < NC; ++c) m = fmaxf(m, v[c]);
                float s = 0.f;
                #pragma unroll
                for (int c = 0; c < NC; ++c) { v[c] = __expf(v[c] - m); s += v[c]; }
                const float inv = __builtin_amdgcn_rcpf(s);

                #pragma unroll
                for (int c = 0; c < NC; ++c) {
                    const float p   = v[c] * inv;
                    const bool  hit = (t == c);
                    sWP[c] += wt * p;
                    sI[c]  += hit ? wt * p : 0.f;
                    sOH[c] += hit ? wt : 0.f;
                }
            }
        } else {
            // ---- tail chunk: per-token guarded scalar ----
            for (int j = 0; j < TPT; ++j) {
                const int a = tokBase + tid * TPT + j;
                if (a >= n) break;
                const int  t    = targets[a];
                const bool last = (a == n - 1);
                const int  tn   = last ? 0 : targets[a + 1];

                float wt = 1.0f;
                if (t == 1) wt = 3.0f;
                const int nxt_dup = last ? t : tn;
                if (t == 2 && nxt_dup != 2) wt = 2.5f;
                if (!last && tn == 1) wt = 1.5f;

                float v[NC];
                #pragma unroll
                for (int c = 0; c < NC; ++c) v[c] = logits[(size_t)a * NC + c];
                float m = v[0];
                #pragma unroll
                for (int c = 1; c < NC; ++c) m = fmaxf(m, v[c]);
                float s = 0.f;
                #pragma unroll
                for (int c = 0; c < NC; ++c) { v[c] = __expf(v[c] - m); s += v[c]; }
                const float inv = __builtin_amdgcn_rcpf(s);

                #pragma unroll
                for (int c = 0; c < NC; ++c) {
                    const float p   = v[c] * inv;
                    const bool  hit = (t == c);
                    sWP[c] += wt * p;
                    sI[c]  += hit ? wt * p : 0.f;
                    sOH[c] += hit ? wt : 0.f;
                }
            }
        }
    }

    // ---- wave shuffle reduction (64 lanes) ----
    #pragma unroll
    for (int off = 32; off; off >>= 1) {
        #pragma unroll
        for (int c = 0; c < NC; ++c) {
            sWP[c] += __shfl_down(sWP[c], off);
            sI[c]  += __shfl_down(sI[c], off);
            sOH[c] += __shfl_down(sOH[c], off);
        }
    }

    // ---- cross-wave LDS reduction, per-block partial store ----
    if (l == 0) {
        #pragma unroll
        for (int c = 0; c < NC; ++c) {
            red[w][c]      = sWP[c];
            red[w][9 + c]  = sI[c];
            red[w][18 + c] = sOH[c];
        }
    }
    __syncthreads();
    if (tid < 27) {
        partials[blockIdx.x * 32 + tid] =
            red[0][tid] + red[1][tid] + red[2][tid] + red[3][tid];
    }
}

__global__ __launch_bounds__(1024) void dice_reduce(
    const float* __restrict__ partials,
    float*       __restrict__ out,
    int nblocks)
{
    const int c = threadIdx.x & 31;   // class-slot 0..31 (27 used)
    const int r = threadIdx.x >> 5;   // 0..31
    float s = 0.f;
    if (c < 27) {
        for (int b = r; b < nblocks; b += 32)
            s += partials[b * 32 + c];
    }
    __shared__ float acc[32][33];
    acc[r][c] = s;
    __syncthreads();

    __shared__ float A[32];
    if (threadIdx.x < 32) {
        float tot = 0.f;
        #pragma unroll
        for (int k = 0; k < 32; ++k) tot += acc[k][threadIdx.x];
        A[threadIdx.x] = tot;
    }
    __syncthreads();
    if (threadIdx.x == 0) {
        float dsum = 0.f;
        #pragma unroll
        for (int cc = 0; cc < NC; ++cc) {
            const float inter = A[9 + cc];
            const float den   = A[cc] + A[18 + cc];
            dsum += (2.f * inter + 1e-5f) / (den + 1e-5f);
        }
        out[0] = 1.f - dsum * (1.f / 9.f);
    }
}

extern "C" void kernel_launch(void* const* d_in, const int* in_sizes, int n_in,
                              void* d_out, int out_size, void* d_ws, size_t ws_size,
                              hipStream_t stream)
{
    const float* logits   = (const float*)d_in[0];
    const int*   targets  = (const int*)d_in[1];
    float*       out      = (float*)d_out;
    float*       partials = (float*)d_ws;
    const int n = in_sizes[1];           // token count (in_sizes[0] = n*9)

    const int nChunks = (n + CHUNK - 1) / CHUNK;
    const int grid = nChunks < GRID ? nChunks : GRID;
    dice_partial<<<grid, BLOCK, 0, stream>>>(logits, targets, partials, n);
    dice_reduce<<<1, 1024, 0, stream>>>(partials, out, grid);
}